// Round 2
// baseline (1188.445 us; speedup 1.0000x reference)
//
#include <hip/hip_runtime.h>
#include <hip/hip_bf16.h>

// Problem constants (from reference)
#define N0 100000
#define N1 50000
#define N2 20000
#define DD 128
#define E0 600000
#define E1 300000

__device__ __forceinline__ float cvt(float v) { return v; }
__device__ __forceinline__ float cvt(__hip_bfloat16 v) { return __bfloat162float(v); }
__device__ __forceinline__ void stv(float* p, float v) { *p = v; }
__device__ __forceinline__ void stv(__hip_bfloat16* p, float v) { *p = __float2bfloat16(v); }

// ---------------------------------------------------------------------------
// Scatter: for each edge e, acc[dst[e]][c] += x[src[e]][c]; deg[dst[e]] += 1.
// 128 threads per edge (one per feature column).
// ---------------------------------------------------------------------------
template <typename TSRC>
__global__ __launch_bounds__(256) void scatter_kernel(
    const TSRC* __restrict__ x,
    const int* __restrict__ src,
    const int* __restrict__ dst,
    float* __restrict__ acc,
    float* __restrict__ deg,
    int E)
{
    int tid = blockIdx.x * 256 + threadIdx.x;
    int e = tid >> 7;
    int c = tid & 127;
    if (e >= E) return;
    int s = src[e];
    int d = dst[e];
    float v = cvt(x[(long)s * DD + c]);
    atomicAdd(&acc[(long)d * DD + c], v);
    if (c == 0) atomicAdd(&deg[d], 1.0f);
}

// ---------------------------------------------------------------------------
// Combine: out[r][j] = act( self[r]@(Ws0+Ws1) + (acc0[r]/deg0)@Wn0
//                          + (acc1[r]/deg1)@Wn1 + b0 + b1 )
// Block: 256 threads, 16 rows per block. A-rows staged in LDS (fp32),
// weights (fp32) streamed from global (hot in L1/L2, amortized over 16 rows).
// ---------------------------------------------------------------------------
template <bool RELU, typename TSELF, typename TOUT>
__global__ __launch_bounds__(256) void combine_kernel(
    const TSELF* __restrict__ xself,
    const float* __restrict__ acc0, const float* __restrict__ deg0,
    const float* __restrict__ acc1, const float* __restrict__ deg1,
    const float* __restrict__ Ws0, const float* __restrict__ Ws1,
    const float* __restrict__ Wn0, const float* __restrict__ Wn1,
    const float* __restrict__ b0, const float* __restrict__ b1,
    TOUT* __restrict__ out, int M)
{
    __shared__ float shS[16][DD];
    __shared__ float shN0[16][DD];
    __shared__ float shN1[16][DD];

    const int t = threadIdx.x;
    const int r0 = blockIdx.x * 16;

    // Stage A-rows: self, hn0, hn1 (mean = acc/max(deg,1))
    for (int idx = t; idx < 16 * DD; idx += 256) {
        int rl = idx >> 7;
        int c = idx & 127;
        int row = r0 + rl;
        float vs = 0.f, v0 = 0.f, v1 = 0.f;
        if (row < M) {
            long off = (long)row * DD + c;
            vs = cvt(xself[off]);
            float d0 = deg0[row]; d0 = d0 > 1.f ? d0 : 1.f;
            float d1 = deg1[row]; d1 = d1 > 1.f ? d1 : 1.f;
            v0 = acc0[off] / d0;
            v1 = acc1[off] / d1;
        }
        shS[rl][c] = vs;
        shN0[rl][c] = v0;
        shN1[rl][c] = v1;
    }
    __syncthreads();

    const int j = t & 127;
    const int rbase = (t >> 7) * 8;

    float accv[8];
    const float bias = b0[j] + b1[j];
#pragma unroll
    for (int i = 0; i < 8; i++) accv[i] = bias;

    for (int k4 = 0; k4 < DD; k4 += 4) {
        float ws[4], w0[4], w1[4];
#pragma unroll
        for (int kk = 0; kk < 4; kk++) {
            int off = (k4 + kk) * DD + j;
            ws[kk] = Ws0[off] + Ws1[off];
            w0[kk] = Wn0[off];
            w1[kk] = Wn1[off];
        }
#pragma unroll
        for (int i = 0; i < 8; i++) {
            const float4 as = *(const float4*)&shS[rbase + i][k4];
            const float4 a0 = *(const float4*)&shN0[rbase + i][k4];
            const float4 a1 = *(const float4*)&shN1[rbase + i][k4];
            float a = accv[i];
            a += as.x * ws[0] + as.y * ws[1] + as.z * ws[2] + as.w * ws[3];
            a += a0.x * w0[0] + a0.y * w0[1] + a0.z * w0[2] + a0.w * w0[3];
            a += a1.x * w1[0] + a1.y * w1[1] + a1.z * w1[2] + a1.w * w1[3];
            accv[i] = a;
        }
    }

#pragma unroll
    for (int i = 0; i < 8; i++) {
        int row = r0 + rbase + i;
        if (row < M) {
            float v = accv[i];
            if (RELU) v = v > 0.f ? v : 0.f;
            stv(&out[(long)row * DD + j], v);
        }
    }
}

extern "C" void kernel_launch(void* const* d_in, const int* in_sizes, int n_in,
                              void* d_out, int out_size, void* d_ws, size_t ws_size,
                              hipStream_t stream)
{
    // Inputs (setup_inputs dict order), ALL floats are fp32 per the reference:
    const float* x = (const float*)d_in[0];
    const int* e0_src_r0 = (const int*)d_in[1];
    const int* e0_dst_r0 = (const int*)d_in[2];
    const int* e0_src_r1 = (const int*)d_in[3];
    const int* e0_dst_r1 = (const int*)d_in[4];
    const int* e1_src_r0 = (const int*)d_in[5];
    const int* e1_dst_r0 = (const int*)d_in[6];
    const int* e1_src_r1 = (const int*)d_in[7];
    const int* e1_dst_r1 = (const int*)d_in[8];
    const float* Ws1_r0 = (const float*)d_in[9];
    const float* Wn1_r0 = (const float*)d_in[10];
    const float* Ws1_r1 = (const float*)d_in[11];
    const float* Wn1_r1 = (const float*)d_in[12];
    const float* Ws2_r0 = (const float*)d_in[13];
    const float* Wn2_r0 = (const float*)d_in[14];
    const float* Ws2_r1 = (const float*)d_in[15];
    const float* Wn2_r1 = (const float*)d_in[16];
    const float* b1_r0 = (const float*)d_in[17];
    const float* b1_r1 = (const float*)d_in[18];
    const float* b2_r0 = (const float*)d_in[19];
    const float* b2_r1 = (const float*)d_in[20];
    float* out = (float*)d_out;

    // Workspace layout (64.4 MB peak; layer-2 accumulators reuse layer-1 region):
    //   accA: N1*128 fp32    (layer1 r0 acc; reused as layer2 r0 acc)
    //   accB: N1*128 fp32    (layer1 r1 acc; reused as layer2 r1 acc)
    //   degA: N1 fp32        (reused for layer2 deg r0)
    //   degB: N1 fp32        (reused for layer2 deg r1)
    //   h1  : N1*128 bf16
    float* accA = (float*)d_ws;
    float* accB = accA + (long)N1 * DD;
    float* degA = accB + (long)N1 * DD;
    float* degB = degA + N1;
    __hip_bfloat16* h1 = (__hip_bfloat16*)(degB + N1);

    const size_t acc_region_floats = (size_t)2 * N1 * DD + 2 * N1;

    // ---- Layer 1 ----
    hipMemsetAsync(d_ws, 0, acc_region_floats * sizeof(float), stream);

    {
        int blocks = (E0 * DD) / 256;
        scatter_kernel<float><<<blocks, 256, 0, stream>>>(x, e0_src_r0, e0_dst_r0, accA, degA, E0);
        scatter_kernel<float><<<blocks, 256, 0, stream>>>(x, e0_src_r1, e0_dst_r1, accB, degB, E0);
    }
    {
        int blocks = (N1 + 15) / 16;
        combine_kernel<true, float, __hip_bfloat16><<<blocks, 256, 0, stream>>>(
            x, accA, degA, accB, degB,
            Ws1_r0, Ws1_r1, Wn1_r0, Wn1_r1, b1_r0, b1_r1, h1, N1);
    }

    // ---- Layer 2 (reuse acc region) ----
    hipMemsetAsync(d_ws, 0, acc_region_floats * sizeof(float), stream);

    {
        int blocks = (E1 * DD) / 256;
        scatter_kernel<__hip_bfloat16><<<blocks, 256, 0, stream>>>(h1, e1_src_r0, e1_dst_r0, accA, degA, E1);
        scatter_kernel<__hip_bfloat16><<<blocks, 256, 0, stream>>>(h1, e1_src_r1, e1_dst_r1, accB, degB, E1);
    }
    {
        int blocks = (N2 + 15) / 16;
        combine_kernel<false, __hip_bfloat16, float><<<blocks, 256, 0, stream>>>(
            h1, accA, degA, accB, degB,
            Ws2_r0, Ws2_r1, Wn2_r0, Wn2_r1, b2_r0, b2_r1, out, N2);
    }
}

// Round 3
// 815.886 us; speedup vs baseline: 1.4566x; 1.4566x over previous
//
#include <hip/hip_runtime.h>
#include <hip/hip_bf16.h>

#define N0 100000
#define N1 50000
#define N2 20000
#define DD 128
#define E0 600000
#define E1 300000

__device__ __forceinline__ float cvt(float v) { return v; }
__device__ __forceinline__ float cvt(__hip_bfloat16 v) { return __bfloat162float(v); }
__device__ __forceinline__ void stv(float* p, float v) { *p = v; }
__device__ __forceinline__ void stv(__hip_bfloat16* p, float v) { *p = __float2bfloat16(v); }

__device__ __forceinline__ float2 ld2(const float* p) { return *(const float2*)p; }
__device__ __forceinline__ float2 ld2(const __hip_bfloat16* p) {
    __hip_bfloat162 v = *(const __hip_bfloat162*)p;
    return make_float2(__bfloat162float(v.x), __bfloat162float(v.y));
}

// ---------------------------------------------------------------------------
// CSR build: histogram -> exclusive scan (2-level) -> fill
// Rows are concatenated across the 2 relations: row index rel*M + dst.
// ---------------------------------------------------------------------------
__global__ __launch_bounds__(256) void hist_kernel(
    const int* __restrict__ dst, int* __restrict__ counts, int E, int base)
{
    int e = blockIdx.x * 256 + threadIdx.x;
    if (e < E) atomicAdd(&counts[base + dst[e]], 1);
}

// scan1: each block scans 1024 elements (4/thread), writes block-local
// exclusive scan to out and the block total to blk_sums.
__global__ __launch_bounds__(256) void scan1_kernel(
    const int* __restrict__ in, int* __restrict__ out, int* __restrict__ blk_sums, int n)
{
    __shared__ int sh[256];
    const int t = threadIdx.x;
    const int b0 = blockIdx.x * 1024;
    int v[4]; int s = 0;
#pragma unroll
    for (int i = 0; i < 4; i++) {
        int idx = b0 + t * 4 + i;
        v[i] = (idx < n) ? in[idx] : 0;
        s += v[i];
    }
    sh[t] = s;
    __syncthreads();
    for (int off = 1; off < 256; off <<= 1) {
        int tmp = (t >= off) ? sh[t - off] : 0;
        __syncthreads();
        sh[t] += tmp;
        __syncthreads();
    }
    int excl = sh[t] - s;
#pragma unroll
    for (int i = 0; i < 4; i++) {
        int idx = b0 + t * 4 + i;
        if (idx < n) out[idx] = excl;
        excl += v[i];
    }
    if (t == 255) blk_sums[blockIdx.x] = sh[255];
}

// scan2: single block, exclusive scan of blk_sums in place (nb <= 256)
__global__ __launch_bounds__(256) void scan2_kernel(int* __restrict__ blk_sums, int nb)
{
    __shared__ int sh[256];
    const int t = threadIdx.x;
    int orig = (t < nb) ? blk_sums[t] : 0;
    sh[t] = orig;
    __syncthreads();
    for (int off = 1; off < 256; off <<= 1) {
        int tmp = (t >= off) ? sh[t - off] : 0;
        __syncthreads();
        sh[t] += tmp;
        __syncthreads();
    }
    if (t < nb) blk_sums[t] = sh[t] - orig;
}

// scan3: add block offsets; write total sentinel row_ptr[n]
__global__ __launch_bounds__(256) void scan3_kernel(
    int* __restrict__ row_ptr, const int* __restrict__ blk_sums,
    const int* __restrict__ counts, int n)
{
    int idx = blockIdx.x * 256 + threadIdx.x;
    if (idx < n) {
        int v = row_ptr[idx] + blk_sums[idx >> 10];
        row_ptr[idx] = v;
        if (idx == n - 1) row_ptr[n] = v + counts[idx];
    }
}

__global__ __launch_bounds__(256) void fill_kernel(
    const int* __restrict__ src, const int* __restrict__ dst,
    const int* __restrict__ row_ptr, int* __restrict__ cursor,
    int* __restrict__ eidx, int E, int base)
{
    int e = blockIdx.x * 256 + threadIdx.x;
    if (e >= E) return;
    int d = base + dst[e];
    int pos = atomicAdd(&cursor[d], 1);
    eidx[row_ptr[d] + pos] = src[e];
}

// ---------------------------------------------------------------------------
// Fused aggregate + combine:
//   out[r] = act( self[r]@(Ws0+Ws1) + mean_r0[r]@Wn0 + mean_r1[r]@Wn1 + b0+b1 )
// Block = 256 threads (4 waves), 16 dst rows.
// Phase A: stage self rows in LDS. Phase B: per-wave CSR gather-mean into LDS.
// Phase C: fp32 register GEMM, weights streamed from global (L1/L2 hot).
// ---------------------------------------------------------------------------
template <bool RELU, typename TSRC, typename TOUT>
__global__ __launch_bounds__(256) void fused_combine_kernel(
    const TSRC* __restrict__ xsrc,          // node features (self + gather source)
    const int* __restrict__ row_ptr,        // 2*M+1 concat-CSR
    const int* __restrict__ eidx,
    const float* __restrict__ Ws0, const float* __restrict__ Ws1,
    const float* __restrict__ Wn0, const float* __restrict__ Wn1,
    const float* __restrict__ b0, const float* __restrict__ b1,
    TOUT* __restrict__ out, int M)
{
    __shared__ float shS[16][DD];
    __shared__ float shN0[16][DD];
    __shared__ float shN1[16][DD];

    const int t = threadIdx.x;
    const int r0 = blockIdx.x * 16;

    // Phase A: self rows
    for (int idx = t; idx < 16 * DD; idx += 256) {
        int rl = idx >> 7;
        int c = idx & 127;
        int row = r0 + rl;
        shS[rl][c] = (row < M) ? cvt(xsrc[(long)row * DD + c]) : 0.f;
    }

    // Phase B: gather-mean per wave (wave w handles rows w, w+4, w+8, w+12)
    const int wave = t >> 6;
    const int lane = t & 63;
    for (int rr = wave; rr < 16; rr += 4) {
        int row = r0 + rr;
#pragma unroll
        for (int rel = 0; rel < 2; rel++) {
            float sx = 0.f, sy = 0.f;
            int cnt = 0;
            if (row < M) {
                int rbase = rel * M + row;
                int beg = row_ptr[rbase];
                int end = row_ptr[rbase + 1];
                cnt = end - beg;
                for (int k = beg; k < end; k++) {
                    int sidx = eidx[k];
                    float2 v = ld2(&xsrc[(long)sidx * DD + lane * 2]);
                    sx += v.x; sy += v.y;
                }
            }
            float inv = 1.f / (float)(cnt > 1 ? cnt : 1);
            float* sh = (rel == 0) ? &shN0[rr][0] : &shN1[rr][0];
            sh[lane * 2]     = sx * inv;
            sh[lane * 2 + 1] = sy * inv;
        }
    }
    __syncthreads();

    // Phase C: GEMM. thread -> col j = t&127, rows rbase..rbase+7
    const int j = t & 127;
    const int rbase = (t >> 7) * 8;

    float accv[8];
    const float bias = b0[j] + b1[j];
#pragma unroll
    for (int i = 0; i < 8; i++) accv[i] = bias;

    for (int k4 = 0; k4 < DD; k4 += 4) {
        float ws[4], w0[4], w1[4];
#pragma unroll
        for (int kk = 0; kk < 4; kk++) {
            int off = (k4 + kk) * DD + j;
            ws[kk] = Ws0[off] + Ws1[off];
            w0[kk] = Wn0[off];
            w1[kk] = Wn1[off];
        }
#pragma unroll
        for (int i = 0; i < 8; i++) {
            const float4 as = *(const float4*)&shS[rbase + i][k4];
            const float4 a0 = *(const float4*)&shN0[rbase + i][k4];
            const float4 a1 = *(const float4*)&shN1[rbase + i][k4];
            float a = accv[i];
            a += as.x * ws[0] + as.y * ws[1] + as.z * ws[2] + as.w * ws[3];
            a += a0.x * w0[0] + a0.y * w0[1] + a0.z * w0[2] + a0.w * w0[3];
            a += a1.x * w1[0] + a1.y * w1[1] + a1.z * w1[2] + a1.w * w1[3];
            accv[i] = a;
        }
    }

#pragma unroll
    for (int i = 0; i < 8; i++) {
        int row = r0 + rbase + i;
        if (row < M) {
            float v = accv[i];
            if (RELU) v = v > 0.f ? v : 0.f;
            stv(&out[(long)row * DD + j], v);
        }
    }
}

// ---------------------------------------------------------------------------

static inline void build_csr(const int* src0, const int* dst0,
                             const int* src1, const int* dst1,
                             int E, int M,
                             int* counts, int* cursor, int* row_ptr,
                             int* blk_sums, int* eidx,
                             size_t zero_ints, hipStream_t stream)
{
    hipMemsetAsync(counts, 0, zero_ints * sizeof(int), stream);  // counts+cursor
    int eb = (E + 255) / 256;
    hist_kernel<<<eb, 256, 0, stream>>>(dst0, counts, E, 0);
    hist_kernel<<<eb, 256, 0, stream>>>(dst1, counts, E, M);
    int n = 2 * M;
    int nb = (n + 1023) / 1024;
    scan1_kernel<<<nb, 256, 0, stream>>>(counts, row_ptr, blk_sums, n);
    scan2_kernel<<<1, 256, 0, stream>>>(blk_sums, nb);
    scan3_kernel<<<(n + 255) / 256, 256, 0, stream>>>(row_ptr, blk_sums, counts, n);
    fill_kernel<<<eb, 256, 0, stream>>>(src0, dst0, row_ptr, cursor, eidx, E, 0);
    fill_kernel<<<eb, 256, 0, stream>>>(src1, dst1, row_ptr, cursor, eidx, E, M);
}

extern "C" void kernel_launch(void* const* d_in, const int* in_sizes, int n_in,
                              void* d_out, int out_size, void* d_ws, size_t ws_size,
                              hipStream_t stream)
{
    const float* x = (const float*)d_in[0];
    const int* e0_src_r0 = (const int*)d_in[1];
    const int* e0_dst_r0 = (const int*)d_in[2];
    const int* e0_src_r1 = (const int*)d_in[3];
    const int* e0_dst_r1 = (const int*)d_in[4];
    const int* e1_src_r0 = (const int*)d_in[5];
    const int* e1_dst_r0 = (const int*)d_in[6];
    const int* e1_src_r1 = (const int*)d_in[7];
    const int* e1_dst_r1 = (const int*)d_in[8];
    const float* Ws1_r0 = (const float*)d_in[9];
    const float* Wn1_r0 = (const float*)d_in[10];
    const float* Ws1_r1 = (const float*)d_in[11];
    const float* Wn1_r1 = (const float*)d_in[12];
    const float* Ws2_r0 = (const float*)d_in[13];
    const float* Wn2_r0 = (const float*)d_in[14];
    const float* Ws2_r1 = (const float*)d_in[15];
    const float* Wn2_r1 = (const float*)d_in[16];
    const float* b1_r0 = (const float*)d_in[17];
    const float* b1_r1 = (const float*)d_in[18];
    const float* b2_r0 = (const float*)d_in[19];
    const float* b2_r1 = (const float*)d_in[20];
    float* out = (float*)d_out;

    // Workspace (~18.4 MB):
    //   h1       : N1*DD bf16
    //   counts   : 2*N1 int      (zeroed with cursor each layer)
    //   cursor   : 2*N1 int
    //   row_ptr  : 2*N1+2 int
    //   blk_sums : 512 int
    //   eidx     : 2*E0 int
    __hip_bfloat16* h1 = (__hip_bfloat16*)d_ws;
    int* counts   = (int*)(h1 + (size_t)N1 * DD);
    int* cursor   = counts + 2 * N1;
    int* row_ptr  = cursor + 2 * N1;
    int* blk_sums = row_ptr + 2 * N1 + 2;
    int* eidx     = blk_sums + 512;

    // ---- Layer 1 ----
    build_csr(e0_src_r0, e0_dst_r0, e0_src_r1, e0_dst_r1, E0, N1,
              counts, cursor, row_ptr, blk_sums, eidx, (size_t)4 * N1, stream);
    fused_combine_kernel<true, float, __hip_bfloat16>
        <<<(N1 + 15) / 16, 256, 0, stream>>>(
            x, row_ptr, eidx,
            Ws1_r0, Ws1_r1, Wn1_r0, Wn1_r1, b1_r0, b1_r1, h1, N1);

    // ---- Layer 2 ----
    build_csr(e1_src_r0, e1_dst_r0, e1_src_r1, e1_dst_r1, E1, N2,
              counts, cursor, row_ptr, blk_sums, eidx, (size_t)4 * N1, stream);
    fused_combine_kernel<false, __hip_bfloat16, float>
        <<<(N2 + 15) / 16, 256, 0, stream>>>(
            h1, row_ptr, eidx,
            Ws2_r0, Ws2_r1, Wn2_r0, Wn2_r1, b2_r0, b2_r1, out, N2);
}

// Round 4
// 586.031 us; speedup vs baseline: 2.0280x; 1.3922x over previous
//
#include <hip/hip_runtime.h>
#include <hip/hip_bf16.h>

#define N0 100000
#define N1 50000
#define N2 20000
#define DD 128
#define E0 600000
#define E1 300000

__device__ __forceinline__ float cvt(float v) { return v; }
__device__ __forceinline__ float cvt(__hip_bfloat16 v) { return __bfloat162float(v); }
__device__ __forceinline__ void stv(float* p, float v) { *p = v; }
__device__ __forceinline__ void stv(__hip_bfloat16* p, float v) { *p = __float2bfloat16(v); }

__device__ __forceinline__ float2 ld2(const float* p) { return *(const float2*)p; }
__device__ __forceinline__ float2 ld2(const __hip_bfloat16* p) {
    __hip_bfloat162 v = *(const __hip_bfloat162*)p;
    return make_float2(__bfloat162float(v.x), __bfloat162float(v.y));
}
__device__ __forceinline__ void st2bf(__hip_bfloat16* p, float a, float b) {
    __hip_bfloat162 v;
    v.x = __float2bfloat16(a);
    v.y = __float2bfloat16(b);
    *(__hip_bfloat162*)p = v;
}

// ---------------------------------------------------------------------------
// fp32 -> bf16 cast of the gather table (x). 4 elements / thread.
// ---------------------------------------------------------------------------
__global__ __launch_bounds__(256) void cast_kernel(
    const float* __restrict__ x, __hip_bfloat16* __restrict__ xb, int n4)
{
    int i = blockIdx.x * 256 + threadIdx.x;
    if (i >= n4) return;
    float4 v = ((const float4*)x)[i];
    st2bf(xb + (size_t)i * 4, v.x, v.y);
    st2bf(xb + (size_t)i * 4 + 2, v.z, v.w);
}

// ---------------------------------------------------------------------------
// CSR build: histogram -> exclusive scan (2-level) -> fill
// Rows concatenated across the 2 relations: row index rel*M + dst.
// ---------------------------------------------------------------------------
__global__ __launch_bounds__(256) void hist_kernel(
    const int* __restrict__ dst, int* __restrict__ counts, int E, int base)
{
    int e = blockIdx.x * 256 + threadIdx.x;
    if (e < E) atomicAdd(&counts[base + dst[e]], 1);
}

__global__ __launch_bounds__(256) void scan1_kernel(
    const int* __restrict__ in, int* __restrict__ out, int* __restrict__ blk_sums, int n)
{
    __shared__ int sh[256];
    const int t = threadIdx.x;
    const int b0 = blockIdx.x * 1024;
    int v[4]; int s = 0;
#pragma unroll
    for (int i = 0; i < 4; i++) {
        int idx = b0 + t * 4 + i;
        v[i] = (idx < n) ? in[idx] : 0;
        s += v[i];
    }
    sh[t] = s;
    __syncthreads();
    for (int off = 1; off < 256; off <<= 1) {
        int tmp = (t >= off) ? sh[t - off] : 0;
        __syncthreads();
        sh[t] += tmp;
        __syncthreads();
    }
    int excl = sh[t] - s;
#pragma unroll
    for (int i = 0; i < 4; i++) {
        int idx = b0 + t * 4 + i;
        if (idx < n) out[idx] = excl;
        excl += v[i];
    }
    if (t == 255) blk_sums[blockIdx.x] = sh[255];
}

__global__ __launch_bounds__(256) void scan2_kernel(int* __restrict__ blk_sums, int nb)
{
    __shared__ int sh[256];
    const int t = threadIdx.x;
    int orig = (t < nb) ? blk_sums[t] : 0;
    sh[t] = orig;
    __syncthreads();
    for (int off = 1; off < 256; off <<= 1) {
        int tmp = (t >= off) ? sh[t - off] : 0;
        __syncthreads();
        sh[t] += tmp;
        __syncthreads();
    }
    if (t < nb) blk_sums[t] = sh[t] - orig;
}

__global__ __launch_bounds__(256) void scan3_kernel(
    int* __restrict__ row_ptr, const int* __restrict__ blk_sums,
    const int* __restrict__ counts, int n)
{
    int idx = blockIdx.x * 256 + threadIdx.x;
    if (idx < n) {
        int v = row_ptr[idx] + blk_sums[idx >> 10];
        row_ptr[idx] = v;
        if (idx == n - 1) row_ptr[n] = v + counts[idx];
    }
}

__global__ __launch_bounds__(256) void fill_kernel(
    const int* __restrict__ src, const int* __restrict__ dst,
    const int* __restrict__ row_ptr, int* __restrict__ cursor,
    int* __restrict__ eidx, int E, int base)
{
    int e = blockIdx.x * 256 + threadIdx.x;
    if (e >= E) return;
    int d = base + dst[e];
    int pos = atomicAdd(&cursor[d], 1);
    eidx[row_ptr[d] + pos] = src[e];
}

// ---------------------------------------------------------------------------
// Aggregation: one wave per CSR segment (rel*M + row). Gather bf16 rows
// (256 B/row), fp32 accumulate, write mean as bf16 to hn[seg][128].
// No LDS, low VGPR -> high occupancy; unroll-4 for outstanding loads.
// ---------------------------------------------------------------------------
__global__ __launch_bounds__(256) void aggregate_kernel(
    const __hip_bfloat16* __restrict__ xb,
    const int* __restrict__ row_ptr,
    const int* __restrict__ eidx,
    __hip_bfloat16* __restrict__ hn,
    int nseg)
{
    int wid = (blockIdx.x * 256 + threadIdx.x) >> 6;
    const int lane = threadIdx.x & 63;
    if (wid >= nseg) return;
    wid = __builtin_amdgcn_readfirstlane(wid);   // provably wave-uniform -> scalar loads

    const int beg = row_ptr[wid];
    const int end = row_ptr[wid + 1];
    const int cnt = end - beg;

    float sx = 0.f, sy = 0.f;
    int k = beg;
    for (; k + 4 <= end; k += 4) {
        int i0 = eidx[k + 0];
        int i1 = eidx[k + 1];
        int i2 = eidx[k + 2];
        int i3 = eidx[k + 3];
        float2 v0 = ld2(&xb[(long)i0 * DD + lane * 2]);
        float2 v1 = ld2(&xb[(long)i1 * DD + lane * 2]);
        float2 v2 = ld2(&xb[(long)i2 * DD + lane * 2]);
        float2 v3 = ld2(&xb[(long)i3 * DD + lane * 2]);
        sx += v0.x + v1.x + v2.x + v3.x;
        sy += v0.y + v1.y + v2.y + v3.y;
    }
    for (; k < end; k++) {
        int i0 = eidx[k];
        float2 v0 = ld2(&xb[(long)i0 * DD + lane * 2]);
        sx += v0.x; sy += v0.y;
    }

    const float inv = 1.f / (float)(cnt > 1 ? cnt : 1);
    st2bf(hn + (long)wid * DD + lane * 2, sx * inv, sy * inv);
}

// ---------------------------------------------------------------------------
// Dense combine: out[r] = act( self[r]@(Ws0+Ws1) + hn0[r]@Wn0 + hn1[r]@Wn1
//                              + b0 + b1 )
// 256 threads, 16 rows/block; A-rows staged fp32 in LDS; weights from global.
// ---------------------------------------------------------------------------
template <bool RELU, typename TSELF, typename TOUT>
__global__ __launch_bounds__(256) void combine_kernel(
    const TSELF* __restrict__ xself,
    const __hip_bfloat16* __restrict__ hn,   // [2*M][128] bf16
    const float* __restrict__ Ws0, const float* __restrict__ Ws1,
    const float* __restrict__ Wn0, const float* __restrict__ Wn1,
    const float* __restrict__ b0, const float* __restrict__ b1,
    TOUT* __restrict__ out, int M)
{
    __shared__ float shS[16][DD];
    __shared__ float shN0[16][DD];
    __shared__ float shN1[16][DD];

    const int t = threadIdx.x;
    const int r0 = blockIdx.x * 16;

    // Stage: 1024 pairs (16 rows x 64 pairs)
    for (int idx = t; idx < 16 * (DD / 2); idx += 256) {
        int rl = idx >> 6;
        int c2 = (idx & 63) * 2;
        int row = r0 + rl;
        float2 vs = make_float2(0.f, 0.f);
        float2 v0 = make_float2(0.f, 0.f);
        float2 v1 = make_float2(0.f, 0.f);
        if (row < M) {
            vs = ld2(&xself[(long)row * DD + c2]);
            v0 = ld2(&hn[(long)row * DD + c2]);
            v1 = ld2(&hn[((long)M + row) * DD + c2]);
        }
        shS[rl][c2] = vs.x;  shS[rl][c2 + 1] = vs.y;
        shN0[rl][c2] = v0.x; shN0[rl][c2 + 1] = v0.y;
        shN1[rl][c2] = v1.x; shN1[rl][c2 + 1] = v1.y;
    }
    __syncthreads();

    const int j = t & 127;
    const int rbase = (t >> 7) * 8;

    float accv[8];
    const float bias = b0[j] + b1[j];
#pragma unroll
    for (int i = 0; i < 8; i++) accv[i] = bias;

    for (int k4 = 0; k4 < DD; k4 += 4) {
        float ws[4], w0[4], w1[4];
#pragma unroll
        for (int kk = 0; kk < 4; kk++) {
            int off = (k4 + kk) * DD + j;
            ws[kk] = Ws0[off] + Ws1[off];
            w0[kk] = Wn0[off];
            w1[kk] = Wn1[off];
        }
#pragma unroll
        for (int i = 0; i < 8; i++) {
            const float4 as = *(const float4*)&shS[rbase + i][k4];
            const float4 a0 = *(const float4*)&shN0[rbase + i][k4];
            const float4 a1 = *(const float4*)&shN1[rbase + i][k4];
            float a = accv[i];
            a += as.x * ws[0] + as.y * ws[1] + as.z * ws[2] + as.w * ws[3];
            a += a0.x * w0[0] + a0.y * w0[1] + a0.z * w0[2] + a0.w * w0[3];
            a += a1.x * w1[0] + a1.y * w1[1] + a1.z * w1[2] + a1.w * w1[3];
            accv[i] = a;
        }
    }

#pragma unroll
    for (int i = 0; i < 8; i++) {
        int row = r0 + rbase + i;
        if (row < M) {
            float v = accv[i];
            if (RELU) v = v > 0.f ? v : 0.f;
            stv(&out[(long)row * DD + j], v);
        }
    }
}

// ---------------------------------------------------------------------------

static inline void build_csr(const int* src0, const int* dst0,
                             const int* src1, const int* dst1,
                             int E, int M,
                             int* counts, int* cursor, int* row_ptr,
                             int* blk_sums, int* eidx,
                             size_t zero_ints, hipStream_t stream)
{
    hipMemsetAsync(counts, 0, zero_ints * sizeof(int), stream);  // counts+cursor
    int eb = (E + 255) / 256;
    hist_kernel<<<eb, 256, 0, stream>>>(dst0, counts, E, 0);
    hist_kernel<<<eb, 256, 0, stream>>>(dst1, counts, E, M);
    int n = 2 * M;
    int nb = (n + 1023) / 1024;
    scan1_kernel<<<nb, 256, 0, stream>>>(counts, row_ptr, blk_sums, n);
    scan2_kernel<<<1, 256, 0, stream>>>(blk_sums, nb);
    scan3_kernel<<<(n + 255) / 256, 256, 0, stream>>>(row_ptr, blk_sums, counts, n);
    fill_kernel<<<eb, 256, 0, stream>>>(src0, dst0, row_ptr, cursor, eidx, E, 0);
    fill_kernel<<<eb, 256, 0, stream>>>(src1, dst1, row_ptr, cursor, eidx, E, M);
}

extern "C" void kernel_launch(void* const* d_in, const int* in_sizes, int n_in,
                              void* d_out, int out_size, void* d_ws, size_t ws_size,
                              hipStream_t stream)
{
    const float* x = (const float*)d_in[0];
    const int* e0_src_r0 = (const int*)d_in[1];
    const int* e0_dst_r0 = (const int*)d_in[2];
    const int* e0_src_r1 = (const int*)d_in[3];
    const int* e0_dst_r1 = (const int*)d_in[4];
    const int* e1_src_r0 = (const int*)d_in[5];
    const int* e1_dst_r0 = (const int*)d_in[6];
    const int* e1_src_r1 = (const int*)d_in[7];
    const int* e1_dst_r1 = (const int*)d_in[8];
    const float* Ws1_r0 = (const float*)d_in[9];
    const float* Wn1_r0 = (const float*)d_in[10];
    const float* Ws1_r1 = (const float*)d_in[11];
    const float* Wn1_r1 = (const float*)d_in[12];
    const float* Ws2_r0 = (const float*)d_in[13];
    const float* Wn2_r0 = (const float*)d_in[14];
    const float* Ws2_r1 = (const float*)d_in[15];
    const float* Wn2_r1 = (const float*)d_in[16];
    const float* b1_r0 = (const float*)d_in[17];
    const float* b1_r1 = (const float*)d_in[18];
    const float* b2_r0 = (const float*)d_in[19];
    const float* b2_r1 = (const float*)d_in[20];
    float* out = (float*)d_out;

    // Workspace (~57.6 MB peak):
    //   region A : N0*DD bf16 (25.6 MB)  = xb (layer-1 gather table),
    //              later reused as h1 (N1*DD bf16, 12.8 MB)
    //   hn       : 2*N1*DD bf16 (25.6 MB), reused across layers
    //   counts   : 2*N1 int
    //   cursor   : 2*N1 int
    //   row_ptr  : 2*N1+2 int
    //   blk_sums : 512 int
    //   eidx     : 2*E0 int (4.8 MB)
    __hip_bfloat16* xb = (__hip_bfloat16*)d_ws;
    __hip_bfloat16* h1 = xb;                       // alias: xb dead before h1 written
    __hip_bfloat16* hn = xb + (size_t)N0 * DD;
    int* counts   = (int*)(hn + (size_t)2 * N1 * DD);
    int* cursor   = counts + 2 * N1;
    int* row_ptr  = cursor + 2 * N1;
    int* blk_sums = row_ptr + 2 * N1 + 2;
    int* eidx     = blk_sums + 512;

    // ---- Layer 1 ----
    cast_kernel<<<(N0 * DD / 4 + 255) / 256, 256, 0, stream>>>(x, xb, N0 * DD / 4);
    build_csr(e0_src_r0, e0_dst_r0, e0_src_r1, e0_dst_r1, E0, N1,
              counts, cursor, row_ptr, blk_sums, eidx, (size_t)4 * N1, stream);
    aggregate_kernel<<<(2 * N1 + 3) / 4, 256, 0, stream>>>(xb, row_ptr, eidx, hn, 2 * N1);
    combine_kernel<true, float, __hip_bfloat16>
        <<<(N1 + 15) / 16, 256, 0, stream>>>(
            x, hn, Ws1_r0, Ws1_r1, Wn1_r0, Wn1_r1, b1_r0, b1_r1, h1, N1);

    // ---- Layer 2 ----
    build_csr(e1_src_r0, e1_dst_r0, e1_src_r1, e1_dst_r1, E1, N2,
              counts, cursor, row_ptr, blk_sums, eidx, (size_t)4 * N1, stream);
    aggregate_kernel<<<(2 * N2 + 3) / 4, 256, 0, stream>>>(h1, row_ptr, eidx, hn, 2 * N2);
    combine_kernel<false, __hip_bfloat16, float>
        <<<(N2 + 15) / 16, 256, 0, stream>>>(
            h1, hn, Ws2_r0, Ws2_r1, Wn2_r0, Wn2_r1, b2_r0, b2_r1, out, N2);
}

// Round 5
// 458.829 us; speedup vs baseline: 2.5902x; 1.2772x over previous
//
#include <hip/hip_runtime.h>
#include <hip/hip_bf16.h>

#define N0 100000
#define N1 50000
#define N2 20000
#define DD 128
#define E0 600000
#define E1 300000

typedef __attribute__((ext_vector_type(8))) short short8;   // 8 bf16 (4 VGPRs)
typedef __attribute__((ext_vector_type(4))) float floatx4;  // MFMA acc

__device__ __forceinline__ float cvt(float v) { return v; }
__device__ __forceinline__ float cvt(__hip_bfloat16 v) { return __bfloat162float(v); }

__device__ __forceinline__ float2 ld2(const float* p) { return *(const float2*)p; }
__device__ __forceinline__ float2 ld2(const __hip_bfloat16* p) {
    __hip_bfloat162 v = *(const __hip_bfloat162*)p;
    return make_float2(__bfloat162float(v.x), __bfloat162float(v.y));
}
__device__ __forceinline__ void st2bf(__hip_bfloat16* p, float a, float b) {
    __hip_bfloat162 v;
    v.x = __float2bfloat16(a);
    v.y = __float2bfloat16(b);
    *(__hip_bfloat162*)p = v;
}
__device__ __forceinline__ short bf16bits(float v) {
    __hip_bfloat16 b = __float2bfloat16(v);
    return *(short*)&b;
}

// ---------------------------------------------------------------------------
// fp32 -> bf16 cast of the gather table (x). 4 elements / thread.
// ---------------------------------------------------------------------------
__global__ __launch_bounds__(256) void cast_kernel(
    const float* __restrict__ x, __hip_bfloat16* __restrict__ xb, int n4)
{
    int i = blockIdx.x * 256 + threadIdx.x;
    if (i >= n4) return;
    float4 v = ((const float4*)x)[i];
    st2bf(xb + (size_t)i * 4, v.x, v.y);
    st2bf(xb + (size_t)i * 4 + 2, v.z, v.w);
}

// ---------------------------------------------------------------------------
// CSR build: histogram -> exclusive scan (2-level) -> fill
// Rows concatenated across the 2 relations: row index rel*M + dst.
// ---------------------------------------------------------------------------
__global__ __launch_bounds__(256) void hist_kernel(
    const int* __restrict__ dst, int* __restrict__ counts, int E, int base)
{
    int e = blockIdx.x * 256 + threadIdx.x;
    if (e < E) atomicAdd(&counts[base + dst[e]], 1);
}

__global__ __launch_bounds__(256) void scan1_kernel(
    const int* __restrict__ in, int* __restrict__ out, int* __restrict__ blk_sums, int n)
{
    __shared__ int sh[256];
    const int t = threadIdx.x;
    const int b0 = blockIdx.x * 1024;
    int v[4]; int s = 0;
#pragma unroll
    for (int i = 0; i < 4; i++) {
        int idx = b0 + t * 4 + i;
        v[i] = (idx < n) ? in[idx] : 0;
        s += v[i];
    }
    sh[t] = s;
    __syncthreads();
    for (int off = 1; off < 256; off <<= 1) {
        int tmp = (t >= off) ? sh[t - off] : 0;
        __syncthreads();
        sh[t] += tmp;
        __syncthreads();
    }
    int excl = sh[t] - s;
#pragma unroll
    for (int i = 0; i < 4; i++) {
        int idx = b0 + t * 4 + i;
        if (idx < n) out[idx] = excl;
        excl += v[i];
    }
    if (t == 255) blk_sums[blockIdx.x] = sh[255];
}

__global__ __launch_bounds__(256) void scan2_kernel(int* __restrict__ blk_sums, int nb)
{
    __shared__ int sh[256];
    const int t = threadIdx.x;
    int orig = (t < nb) ? blk_sums[t] : 0;
    sh[t] = orig;
    __syncthreads();
    for (int off = 1; off < 256; off <<= 1) {
        int tmp = (t >= off) ? sh[t - off] : 0;
        __syncthreads();
        sh[t] += tmp;
        __syncthreads();
    }
    if (t < nb) blk_sums[t] = sh[t] - orig;
}

__global__ __launch_bounds__(256) void scan3_kernel(
    int* __restrict__ row_ptr, const int* __restrict__ blk_sums,
    const int* __restrict__ counts, int n)
{
    int idx = blockIdx.x * 256 + threadIdx.x;
    if (idx < n) {
        int v = row_ptr[idx] + blk_sums[idx >> 10];
        row_ptr[idx] = v;
        if (idx == n - 1) row_ptr[n] = v + counts[idx];
    }
}

__global__ __launch_bounds__(256) void fill_kernel(
    const int* __restrict__ src, const int* __restrict__ dst,
    const int* __restrict__ row_ptr, int* __restrict__ cursor,
    int* __restrict__ eidx, int E, int base)
{
    int e = blockIdx.x * 256 + threadIdx.x;
    if (e >= E) return;
    int d = base + dst[e];
    int pos = atomicAdd(&cursor[d], 1);
    eidx[row_ptr[d] + pos] = src[e];
}

// ---------------------------------------------------------------------------
// Aggregation: one wave per CSR segment. Gather bf16 rows (256 B), fp32
// accumulate, write mean bf16 to hn[seg][128].
// ---------------------------------------------------------------------------
__global__ __launch_bounds__(256) void aggregate_kernel(
    const __hip_bfloat16* __restrict__ xb,
    const int* __restrict__ row_ptr,
    const int* __restrict__ eidx,
    __hip_bfloat16* __restrict__ hn,
    int nseg)
{
    int wid = (blockIdx.x * 256 + threadIdx.x) >> 6;
    const int lane = threadIdx.x & 63;
    if (wid >= nseg) return;
    wid = __builtin_amdgcn_readfirstlane(wid);

    const int beg = row_ptr[wid];
    const int end = row_ptr[wid + 1];
    const int cnt = end - beg;

    float sx = 0.f, sy = 0.f;
    int k = beg;
    for (; k + 4 <= end; k += 4) {
        int i0 = eidx[k + 0];
        int i1 = eidx[k + 1];
        int i2 = eidx[k + 2];
        int i3 = eidx[k + 3];
        float2 v0 = ld2(&xb[(long)i0 * DD + lane * 2]);
        float2 v1 = ld2(&xb[(long)i1 * DD + lane * 2]);
        float2 v2 = ld2(&xb[(long)i2 * DD + lane * 2]);
        float2 v3 = ld2(&xb[(long)i3 * DD + lane * 2]);
        sx += v0.x + v1.x + v2.x + v3.x;
        sy += v0.y + v1.y + v2.y + v3.y;
    }
    for (; k < end; k++) {
        int i0 = eidx[k];
        float2 v0 = ld2(&xb[(long)i0 * DD + lane * 2]);
        sx += v0.x; sy += v0.y;
    }

    const float inv = 1.f / (float)(cnt > 1 ? cnt : 1);
    st2bf(hn + (long)wid * DD + lane * 2, sx * inv, sy * inv);
}

// ---------------------------------------------------------------------------
// Weight prep: pack Wc = [Ws0+Ws1 ; Wn0 ; Wn1] (384 x 128 fp32 -> bf16) into
// MFMA A-fragment order. A-operand (as W^T): lane holds
// A[m = mt*16 + (lane&15)][k = kc*32 + (lane>>4)*8 + j], j=0..7 contiguous.
// Storage: wfrag[((kc*8 + mt)*64 + lane)*8 + j].
// 6144 threads total (kc 0..11, mt 0..7, lane 0..63).
// ---------------------------------------------------------------------------
__global__ __launch_bounds__(256) void prep_weights_kernel(
    const float* __restrict__ Ws0, const float* __restrict__ Ws1,
    const float* __restrict__ Wn0, const float* __restrict__ Wn1,
    short* __restrict__ wfrag)
{
    int t = blockIdx.x * 256 + threadIdx.x;
    if (t >= 12 * 8 * 64) return;
    int lane = t & 63;
    int mt = (t >> 6) & 7;
    int kc = t >> 9;
    int n = mt * 16 + (lane & 15);
    int k0 = kc * 32 + ((lane >> 4) << 3);

    short vals[8];
#pragma unroll
    for (int j = 0; j < 8; j++) {
        int k = k0 + j;
        float w;
        if (k < 128)      w = Ws0[k * DD + n] + Ws1[k * DD + n];
        else if (k < 256) w = Wn0[(k - 128) * DD + n];
        else              w = Wn1[(k - 256) * DD + n];
        vals[j] = bf16bits(w);
    }
    *(short8*)(wfrag + (size_t)t * 8) = *(short8*)vals;
}

// ---------------------------------------------------------------------------
// MFMA combine: D[outcol][node] = Wc^T (A-op) x Xcat^T (B-op), K=384.
// Block = 256 thr (4 waves); wave handles 32 nodes (2 n-tiles) x 128 outcols
// (8 m-tiles). B-frags load straight from row-major node features (16 B);
// A-frags from prepped wfrag (L2-hot). No LDS.
// ---------------------------------------------------------------------------
template <bool RELU, typename TOUT>
__global__ __launch_bounds__(256) void mfma_combine_kernel(
    const __hip_bfloat16* __restrict__ xself,   // [M][128] bf16
    const __hip_bfloat16* __restrict__ hn,      // [2*M][128] bf16
    const short* __restrict__ wfrag,            // 12*8*64*8 bf16 bits
    const float* __restrict__ b0, const float* __restrict__ b1,
    TOUT* __restrict__ out, int M)
{
    const int t = threadIdx.x;
    const int wave = t >> 6;
    const int lane = t & 63;
    const int nsub = lane & 15;
    const int quad = lane >> 4;
    const int base = blockIdx.x * 128 + wave * 32;

    const int node0 = base + nsub;
    const int node1 = base + 16 + nsub;
    const long n0c = node0 < M ? node0 : M - 1;   // clamp for loads
    const long n1c = node1 < M ? node1 : M - 1;

    floatx4 acc[2][8];
#pragma unroll
    for (int nt = 0; nt < 2; nt++)
#pragma unroll
        for (int mt = 0; mt < 8; mt++) acc[nt][mt] = (floatx4){0.f, 0.f, 0.f, 0.f};

    for (int kc = 0; kc < 12; kc++) {
        const __hip_bfloat16* src;
        long r0, r1;
        int koff;
        if (kc < 4)      { src = xself; koff = kc * 32;       r0 = n0c;     r1 = n1c; }
        else if (kc < 8) { src = hn;    koff = (kc - 4) * 32; r0 = n0c;     r1 = n1c; }
        else             { src = hn;    koff = (kc - 8) * 32; r0 = M + n0c; r1 = M + n1c; }

        short8 bf0 = *(const short8*)(src + r0 * DD + koff + quad * 8);
        short8 bf1 = *(const short8*)(src + r1 * DD + koff + quad * 8);
        const short* wbase = wfrag + ((size_t)(kc * 8) * 64 + lane) * 8;
#pragma unroll
        for (int mt = 0; mt < 8; mt++) {
            short8 af = *(const short8*)(wbase + (size_t)mt * 64 * 8);
            acc[0][mt] = __builtin_amdgcn_mfma_f32_16x16x32_bf16(af, bf0, acc[0][mt], 0, 0, 0);
            acc[1][mt] = __builtin_amdgcn_mfma_f32_16x16x32_bf16(af, bf1, acc[1][mt], 0, 0, 0);
        }
    }

    // Epilogue: lane holds node = nt-node, outcols mt*16 + quad*4 + r
#pragma unroll
    for (int nt = 0; nt < 2; nt++) {
        int node = (nt == 0) ? node0 : node1;
        if (node >= M) continue;
#pragma unroll
        for (int mt = 0; mt < 8; mt++) {
            int c0 = mt * 16 + quad * 4;
            float4 bb0 = *(const float4*)(b0 + c0);
            float4 bb1 = *(const float4*)(b1 + c0);
            float v0 = acc[nt][mt][0] + bb0.x + bb1.x;
            float v1 = acc[nt][mt][1] + bb0.y + bb1.y;
            float v2 = acc[nt][mt][2] + bb0.z + bb1.z;
            float v3 = acc[nt][mt][3] + bb0.w + bb1.w;
            if (RELU) {
                v0 = v0 > 0.f ? v0 : 0.f;
                v1 = v1 > 0.f ? v1 : 0.f;
                v2 = v2 > 0.f ? v2 : 0.f;
                v3 = v3 > 0.f ? v3 : 0.f;
            }
            TOUT* p = out + (long)node * DD + c0;
            if constexpr (sizeof(TOUT) == 4) {
                float4 vv = make_float4(v0, v1, v2, v3);
                *(float4*)p = vv;
            } else {
                short vs[4];
                vs[0] = bf16bits(v0); vs[1] = bf16bits(v1);
                vs[2] = bf16bits(v2); vs[3] = bf16bits(v3);
                *(int2*)p = *(int2*)vs;
            }
        }
    }
}

// ---------------------------------------------------------------------------

static inline void build_csr(const int* src0, const int* dst0,
                             const int* src1, const int* dst1,
                             int E, int M,
                             int* counts, int* cursor, int* row_ptr,
                             int* blk_sums, int* eidx,
                             size_t zero_ints, hipStream_t stream)
{
    hipMemsetAsync(counts, 0, zero_ints * sizeof(int), stream);  // counts+cursor
    int eb = (E + 255) / 256;
    hist_kernel<<<eb, 256, 0, stream>>>(dst0, counts, E, 0);
    hist_kernel<<<eb, 256, 0, stream>>>(dst1, counts, E, M);
    int n = 2 * M;
    int nb = (n + 1023) / 1024;
    scan1_kernel<<<nb, 256, 0, stream>>>(counts, row_ptr, blk_sums, n);
    scan2_kernel<<<1, 256, 0, stream>>>(blk_sums, nb);
    scan3_kernel<<<(n + 255) / 256, 256, 0, stream>>>(row_ptr, blk_sums, counts, n);
    fill_kernel<<<eb, 256, 0, stream>>>(src0, dst0, row_ptr, cursor, eidx, E, 0);
    fill_kernel<<<eb, 256, 0, stream>>>(src1, dst1, row_ptr, cursor, eidx, E, M);
}

extern "C" void kernel_launch(void* const* d_in, const int* in_sizes, int n_in,
                              void* d_out, int out_size, void* d_ws, size_t ws_size,
                              hipStream_t stream)
{
    const float* x = (const float*)d_in[0];
    const int* e0_src_r0 = (const int*)d_in[1];
    const int* e0_dst_r0 = (const int*)d_in[2];
    const int* e0_src_r1 = (const int*)d_in[3];
    const int* e0_dst_r1 = (const int*)d_in[4];
    const int* e1_src_r0 = (const int*)d_in[5];
    const int* e1_dst_r0 = (const int*)d_in[6];
    const int* e1_src_r1 = (const int*)d_in[7];
    const int* e1_dst_r1 = (const int*)d_in[8];
    const float* Ws1_r0 = (const float*)d_in[9];
    const float* Wn1_r0 = (const float*)d_in[10];
    const float* Ws1_r1 = (const float*)d_in[11];
    const float* Wn1_r1 = (const float*)d_in[12];
    const float* Ws2_r0 = (const float*)d_in[13];
    const float* Wn2_r0 = (const float*)d_in[14];
    const float* Ws2_r1 = (const float*)d_in[15];
    const float* Wn2_r1 = (const float*)d_in[16];
    const float* b1_r0 = (const float*)d_in[17];
    const float* b1_r1 = (const float*)d_in[18];
    const float* b2_r0 = (const float*)d_in[19];
    const float* b2_r1 = (const float*)d_in[20];
    float* out = (float*)d_out;

    // Workspace (~57.4 MB peak):
    //   xb     : N0*DD bf16 (25.6 MB). h1 aliases xb (row-for-row overwrite
    //            in combine1 epilogue; each row read only by its own wave
    //            before its store -> WAR-safe).
    //   hn     : 2*N1*DD bf16 (25.6 MB), reused across layers
    //   counts/cursor/row_ptr/blk_sums : ~1.2 MB int
    //   eidx   : 2*E0 int (4.8 MB)
    //   wfrag  : 12*8*64*8 bf16 (96 KB), reused across layers
    __hip_bfloat16* xb = (__hip_bfloat16*)d_ws;
    __hip_bfloat16* h1 = xb;
    __hip_bfloat16* hn = xb + (size_t)N0 * DD;
    int* counts   = (int*)(hn + (size_t)2 * N1 * DD);
    int* cursor   = counts + 2 * N1;
    int* row_ptr  = cursor + 2 * N1;
    int* blk_sums = row_ptr + 2 * N1 + 2;
    int* eidx     = blk_sums + 512;
    short* wfrag  = (short*)(eidx + 2 * E0);

    // ---- Layer 1 ----
    cast_kernel<<<(N0 * DD / 4 + 255) / 256, 256, 0, stream>>>(x, xb, N0 * DD / 4);
    build_csr(e0_src_r0, e0_dst_r0, e0_src_r1, e0_dst_r1, E0, N1,
              counts, cursor, row_ptr, blk_sums, eidx, (size_t)4 * N1, stream);
    aggregate_kernel<<<(2 * N1 + 3) / 4, 256, 0, stream>>>(xb, row_ptr, eidx, hn, 2 * N1);
    prep_weights_kernel<<<24, 256, 0, stream>>>(Ws1_r0, Ws1_r1, Wn1_r0, Wn1_r1, wfrag);
    mfma_combine_kernel<true, __hip_bfloat16>
        <<<(N1 + 127) / 128, 256, 0, stream>>>(
            xb, hn, wfrag, b1_r0, b1_r1, h1, N1);

    // ---- Layer 2 ----
    build_csr(e1_src_r0, e1_dst_r0, e1_src_r1, e1_dst_r1, E1, N2,
              counts, cursor, row_ptr, blk_sums, eidx, (size_t)4 * N1, stream);
    aggregate_kernel<<<(2 * N2 + 3) / 4, 256, 0, stream>>>(h1, row_ptr, eidx, hn, 2 * N2);
    prep_weights_kernel<<<24, 256, 0, stream>>>(Ws2_r0, Ws2_r1, Wn2_r0, Wn2_r1, wfrag);
    mfma_combine_kernel<false, float>
        <<<(N2 + 127) / 128, 256, 0, stream>>>(
            h1, hn, wfrag, b2_r0, b2_r1, out, N2);
}

// Round 6
// 405.900 us; speedup vs baseline: 2.9279x; 1.1304x over previous
//
#include <hip/hip_runtime.h>
#include <hip/hip_bf16.h>

#define N0 100000
#define N1 50000
#define N2 20000
#define DD 128
#define E0 600000
#define E1 300000

#define NSEG_TOT (2 * N1 + 2 * N2)          // 140000 concat CSR segments
#define ETOT     (2 * E0 + 2 * E1)          // 1800000 edges
#define SCAN_BLOCKS ((NSEG_TOT + 1023) / 1024)   // 137

#define CAST_BLOCKS 12500                    // N0*DD/4 / 256
#define HIST_BLOCKS 7032                     // ceil(ETOT/256)
#define PREP_BLOCKS 48                       // 2*6144/256
#define PROLOGUE_BLOCKS (CAST_BLOCKS + HIST_BLOCKS + PREP_BLOCKS)

typedef __attribute__((ext_vector_type(8))) short short8;   // 8 bf16 (4 VGPRs)
typedef __attribute__((ext_vector_type(4))) float floatx4;  // MFMA acc

__device__ __forceinline__ void st2bf(__hip_bfloat16* p, float a, float b) {
    __hip_bfloat162 v;
    v.x = __float2bfloat16(a);
    v.y = __float2bfloat16(b);
    *(__hip_bfloat162*)p = v;
}
__device__ __forceinline__ short bf16bits(float v) {
    __hip_bfloat16 b = __float2bfloat16(v);
    return *(short*)&b;
}
__device__ __forceinline__ float bf2f(unsigned short u) {
    return __uint_as_float(((unsigned int)u) << 16);
}
__device__ __forceinline__ float4 ld4bf(const __hip_bfloat16* p) {  // 8B load
    ushort4 u = *(const ushort4*)p;
    return make_float4(bf2f(u.x), bf2f(u.y), bf2f(u.z), bf2f(u.w));
}
__device__ __forceinline__ void st4bf(__hip_bfloat16* p, float4 v) { // 8B store
    short vs[4];
    vs[0] = bf16bits(v.x); vs[1] = bf16bits(v.y);
    vs[2] = bf16bits(v.z); vs[3] = bf16bits(v.w);
    *(int2*)p = *(int2*)vs;
}

// ---------------------------------------------------------------------------
// Edge mapping for the concatenated CSR (4 edge lists):
//   [0,E0)          -> L1 rel0, seg base 0
//   [E0,2E0)        -> L1 rel1, seg base N1
//   [2E0,2E0+E1)    -> L2 rel0, seg base 2*N1
//   [2E0+E1,ETOT)   -> L2 rel1, seg base 2*N1+N2
// ---------------------------------------------------------------------------
struct EdgeRef { const int* src; const int* dst; int e; int base; };
__device__ __forceinline__ EdgeRef edge_map(int e,
    const int* s0, const int* d0, const int* s1, const int* d1,
    const int* s2, const int* d2, const int* s3, const int* d3)
{
    EdgeRef r;
    if (e < E0)               { r.src = s0; r.dst = d0; r.e = e;            r.base = 0; }
    else if (e < 2 * E0)      { r.src = s1; r.dst = d1; r.e = e - E0;       r.base = N1; }
    else if (e < 2 * E0 + E1) { r.src = s2; r.dst = d2; r.e = e - 2 * E0;   r.base = 2 * N1; }
    else                      { r.src = s3; r.dst = d3; r.e = e - 2*E0 - E1; r.base = 2 * N1 + N2; }
    return r;
}

// ---------------------------------------------------------------------------
// Prologue mega-kernel: [cast | hist | weight-prep], split by blockIdx range.
// cast: x fp32 -> xb bf16 (4 elem/thread).
// hist: counts[seg]++ over all 4 edge lists.
// prep: pack Wc = [Ws0+Ws1 ; Wn0 ; Wn1] (384x128) into MFMA A-frag order for
//       both layers. Lane holds A[m=mt*16+(lane&15)][k=kc*32+(lane>>4)*8+j].
// ---------------------------------------------------------------------------
__global__ __launch_bounds__(256) void prologue_kernel(
    const float* __restrict__ x, __hip_bfloat16* __restrict__ xb,
    const int* __restrict__ d0a, const int* __restrict__ d0b,
    const int* __restrict__ d1a, const int* __restrict__ d1b,
    int* __restrict__ counts,
    const float* __restrict__ Ws1a, const float* __restrict__ Ws1b,
    const float* __restrict__ Wn1a, const float* __restrict__ Wn1b,
    const float* __restrict__ Ws2a, const float* __restrict__ Ws2b,
    const float* __restrict__ Wn2a, const float* __restrict__ Wn2b,
    short* __restrict__ wfrag1, short* __restrict__ wfrag2)
{
    const int bid = blockIdx.x;
    if (bid < CAST_BLOCKS) {
        int i = bid * 256 + threadIdx.x;               // < 3.2M exactly
        float4 v = ((const float4*)x)[i];
        st2bf(xb + (size_t)i * 4, v.x, v.y);
        st2bf(xb + (size_t)i * 4 + 2, v.z, v.w);
    } else if (bid < CAST_BLOCKS + HIST_BLOCKS) {
        int e = (bid - CAST_BLOCKS) * 256 + threadIdx.x;
        if (e < ETOT) {
            // hist only needs dst arrays
            EdgeRef r = edge_map(e, nullptr, d0a, nullptr, d0b,
                                    nullptr, d1a, nullptr, d1b);
            atomicAdd(&counts[r.base + r.dst[r.e]], 1);
        }
    } else {
        int p = (bid - CAST_BLOCKS - HIST_BLOCKS) * 256 + threadIdx.x; // < 12288
        int layer = p >= 6144;
        int t = p - layer * 6144;
        int lane = t & 63;
        int mt = (t >> 6) & 7;
        int kc = t >> 9;
        int n = mt * 16 + (lane & 15);
        int k0 = kc * 32 + ((lane >> 4) << 3);
        const float* Wsa = layer ? Ws2a : Ws1a;
        const float* Wsb = layer ? Ws2b : Ws1b;
        const float* Wna = layer ? Wn2a : Wn1a;
        const float* Wnb = layer ? Wn2b : Wn1b;
        short* wf = layer ? wfrag2 : wfrag1;
        short vals[8];
#pragma unroll
        for (int j = 0; j < 8; j++) {
            int k = k0 + j;
            float w;
            if (k < 128)      w = Wsa[k * DD + n] + Wsb[k * DD + n];
            else if (k < 256) w = Wna[(k - 128) * DD + n];
            else              w = Wnb[(k - 256) * DD + n];
            vals[j] = bf16bits(w);
        }
        *(short8*)(wf + (size_t)t * 8) = *(short8*)vals;
    }
}

// ---------------------------------------------------------------------------
// scan1: block-local exclusive scan of counts (1024/block), block sums out.
// ---------------------------------------------------------------------------
__global__ __launch_bounds__(256) void scan1_kernel(
    const int* __restrict__ in, int* __restrict__ out, int* __restrict__ blk_sums, int n)
{
    __shared__ int sh[256];
    const int t = threadIdx.x;
    const int b0 = blockIdx.x * 1024;
    int v[4]; int s = 0;
#pragma unroll
    for (int i = 0; i < 4; i++) {
        int idx = b0 + t * 4 + i;
        v[i] = (idx < n) ? in[idx] : 0;
        s += v[i];
    }
    sh[t] = s;
    __syncthreads();
    for (int off = 1; off < 256; off <<= 1) {
        int tmp = (t >= off) ? sh[t - off] : 0;
        __syncthreads();
        sh[t] += tmp;
        __syncthreads();
    }
    int excl = sh[t] - s;
#pragma unroll
    for (int i = 0; i < 4; i++) {
        int idx = b0 + t * 4 + i;
        if (idx < n) out[idx] = excl;
        excl += v[i];
    }
    if (t == 255) blk_sums[blockIdx.x] = sh[255];
}

// ---------------------------------------------------------------------------
// scan23: every block re-scans blk_sums (nb<=256) in LDS, adds its own
// exclusive prefix to its 1024 row_ptr entries; sentinel is constant ETOT.
// ---------------------------------------------------------------------------
__global__ __launch_bounds__(256) void scan23_kernel(
    int* __restrict__ row_ptr, const int* __restrict__ blk_sums, int n, int nb)
{
    __shared__ int sh[256];
    const int t = threadIdx.x;
    int orig = (t < nb) ? blk_sums[t] : 0;
    sh[t] = orig;
    __syncthreads();
    for (int off = 1; off < 256; off <<= 1) {
        int tmp = (t >= off) ? sh[t - off] : 0;
        __syncthreads();
        sh[t] += tmp;
        __syncthreads();
    }
    __shared__ int myoff;
    if (t == blockIdx.x) myoff = sh[t] - orig;   // exclusive prefix for this block
    __syncthreads();
    const int b0 = blockIdx.x * 1024;
#pragma unroll
    for (int i = 0; i < 4; i++) {
        int idx = b0 + t * 4 + i;
        if (idx < n) row_ptr[idx] += myoff;
    }
    if (blockIdx.x == 0 && t == 0) row_ptr[n] = ETOT;
}

// ---------------------------------------------------------------------------
// fill: scatter edge src indices into CSR order (all 4 lists in one pass).
// ---------------------------------------------------------------------------
__global__ __launch_bounds__(256) void fill_kernel(
    const int* __restrict__ s0a, const int* __restrict__ d0a,
    const int* __restrict__ s0b, const int* __restrict__ d0b,
    const int* __restrict__ s1a, const int* __restrict__ d1a,
    const int* __restrict__ s1b, const int* __restrict__ d1b,
    const int* __restrict__ row_ptr, int* __restrict__ cursor,
    int* __restrict__ eidx)
{
    int e = blockIdx.x * 256 + threadIdx.x;
    if (e >= ETOT) return;
    EdgeRef r = edge_map(e, s0a, d0a, s0b, d0b, s1a, d1a, s1b, d1b);
    int d = r.base + r.dst[r.e];
    int pos = atomicAdd(&cursor[d], 1);
    eidx[row_ptr[d] + pos] = r.src[r.e];
}

// ---------------------------------------------------------------------------
// Aggregation: one wave per CSR segment. 8 B/lane loads -> 2 neighbor rows
// per wave-iteration (half-waves), cross-half shfl_xor reduce at the end.
// ---------------------------------------------------------------------------
__global__ __launch_bounds__(256) void aggregate_kernel(
    const __hip_bfloat16* __restrict__ xb,
    const int* __restrict__ row_ptr,
    const int* __restrict__ eidx,
    __hip_bfloat16* __restrict__ hn,
    int nseg)
{
    int wid = (blockIdx.x * 256 + threadIdx.x) >> 6;
    const int lane = threadIdx.x & 63;
    if (wid >= nseg) return;
    wid = __builtin_amdgcn_readfirstlane(wid);

    const int beg = row_ptr[wid];
    const int end = row_ptr[wid + 1];
    const int cnt = end - beg;
    const int half = lane >> 5;
    const int l32 = lane & 31;

    float4 s = make_float4(0.f, 0.f, 0.f, 0.f);
    int k = beg;
    for (; k + 4 <= end; k += 4) {
        int i0 = eidx[k + 0];
        int i1 = eidx[k + 1];
        int i2 = eidx[k + 2];
        int i3 = eidx[k + 3];
        int ra = half ? i1 : i0;
        int rb = half ? i3 : i2;
        float4 va = ld4bf(xb + (long)ra * DD + l32 * 4);
        float4 vb = ld4bf(xb + (long)rb * DD + l32 * 4);
        s.x += va.x + vb.x; s.y += va.y + vb.y;
        s.z += va.z + vb.z; s.w += va.w + vb.w;
    }
    if (k + 2 <= end) {
        int i0 = eidx[k];
        int i1 = eidx[k + 1];
        int r = half ? i1 : i0;
        float4 v = ld4bf(xb + (long)r * DD + l32 * 4);
        s.x += v.x; s.y += v.y; s.z += v.z; s.w += v.w;
        k += 2;
    }
    if (k < end && !half) {          // odd tail row: half 0 only
        int i0 = eidx[k];
        float4 v = ld4bf(xb + (long)i0 * DD + l32 * 4);
        s.x += v.x; s.y += v.y; s.z += v.z; s.w += v.w;
    }

    // cross-half reduce (lane ^ 32 holds the other partial of the same cols)
    s.x += __shfl_xor(s.x, 32);
    s.y += __shfl_xor(s.y, 32);
    s.z += __shfl_xor(s.z, 32);
    s.w += __shfl_xor(s.w, 32);

    if (!half) {
        const float inv = 1.f / (float)(cnt > 1 ? cnt : 1);
        float4 m = make_float4(s.x * inv, s.y * inv, s.z * inv, s.w * inv);
        st4bf(hn + (long)wid * DD + l32 * 4, m);
    }
}

// ---------------------------------------------------------------------------
// MFMA combine: D[outcol][node] = Wc^T (A-op) x Xcat^T (B-op), K=384.
// Wave: 32 nodes (2 n-tiles) x 128 outcols (8 m-tiles). B-frags direct from
// row-major node features; A-frags from prepped wfrag. No LDS.
// ---------------------------------------------------------------------------
template <bool RELU, typename TOUT>
__global__ __launch_bounds__(256) void mfma_combine_kernel(
    const __hip_bfloat16* __restrict__ xself,   // [M][128] bf16
    const __hip_bfloat16* __restrict__ hn,      // [2*M][128] bf16
    const short* __restrict__ wfrag,            // 12*8*64*8 bf16 bits
    const float* __restrict__ b0, const float* __restrict__ b1,
    TOUT* __restrict__ out, int M)
{
    const int t = threadIdx.x;
    const int wave = t >> 6;
    const int lane = t & 63;
    const int nsub = lane & 15;
    const int quad = lane >> 4;
    const int base = blockIdx.x * 128 + wave * 32;

    const int node0 = base + nsub;
    const int node1 = base + 16 + nsub;
    const long n0c = node0 < M ? node0 : M - 1;   // clamp for loads
    const long n1c = node1 < M ? node1 : M - 1;

    floatx4 acc[2][8];
#pragma unroll
    for (int nt = 0; nt < 2; nt++)
#pragma unroll
        for (int mt = 0; mt < 8; mt++) acc[nt][mt] = (floatx4){0.f, 0.f, 0.f, 0.f};

    for (int kc = 0; kc < 12; kc++) {
        const __hip_bfloat16* src;
        long r0, r1;
        int koff;
        if (kc < 4)      { src = xself; koff = kc * 32;       r0 = n0c;     r1 = n1c; }
        else if (kc < 8) { src = hn;    koff = (kc - 4) * 32; r0 = n0c;     r1 = n1c; }
        else             { src = hn;    koff = (kc - 8) * 32; r0 = M + n0c; r1 = M + n1c; }

        short8 bf0 = *(const short8*)(src + r0 * DD + koff + quad * 8);
        short8 bf1 = *(const short8*)(src + r1 * DD + koff + quad * 8);
        const short* wbase = wfrag + ((size_t)(kc * 8) * 64 + lane) * 8;
#pragma unroll
        for (int mt = 0; mt < 8; mt++) {
            short8 af = *(const short8*)(wbase + (size_t)mt * 64 * 8);
            acc[0][mt] = __builtin_amdgcn_mfma_f32_16x16x32_bf16(af, bf0, acc[0][mt], 0, 0, 0);
            acc[1][mt] = __builtin_amdgcn_mfma_f32_16x16x32_bf16(af, bf1, acc[1][mt], 0, 0, 0);
        }
    }

#pragma unroll
    for (int nt = 0; nt < 2; nt++) {
        int node = (nt == 0) ? node0 : node1;
        if (node >= M) continue;
#pragma unroll
        for (int mt = 0; mt < 8; mt++) {
            int c0 = mt * 16 + quad * 4;
            float4 bb0 = *(const float4*)(b0 + c0);
            float4 bb1 = *(const float4*)(b1 + c0);
            float v0 = acc[nt][mt][0] + bb0.x + bb1.x;
            float v1 = acc[nt][mt][1] + bb0.y + bb1.y;
            float v2 = acc[nt][mt][2] + bb0.z + bb1.z;
            float v3 = acc[nt][mt][3] + bb0.w + bb1.w;
            if (RELU) {
                v0 = v0 > 0.f ? v0 : 0.f;
                v1 = v1 > 0.f ? v1 : 0.f;
                v2 = v2 > 0.f ? v2 : 0.f;
                v3 = v3 > 0.f ? v3 : 0.f;
            }
            TOUT* p = out + (long)node * DD + c0;
            if constexpr (sizeof(TOUT) == 4) {
                *(float4*)p = make_float4(v0, v1, v2, v3);
            } else {
                short vs[4];
                vs[0] = bf16bits(v0); vs[1] = bf16bits(v1);
                vs[2] = bf16bits(v2); vs[3] = bf16bits(v3);
                *(int2*)p = *(int2*)vs;
            }
        }
    }
}

// ---------------------------------------------------------------------------

extern "C" void kernel_launch(void* const* d_in, const int* in_sizes, int n_in,
                              void* d_out, int out_size, void* d_ws, size_t ws_size,
                              hipStream_t stream)
{
    const float* x = (const float*)d_in[0];
    const int* e0_src_r0 = (const int*)d_in[1];
    const int* e0_dst_r0 = (const int*)d_in[2];
    const int* e0_src_r1 = (const int*)d_in[3];
    const int* e0_dst_r1 = (const int*)d_in[4];
    const int* e1_src_r0 = (const int*)d_in[5];
    const int* e1_dst_r0 = (const int*)d_in[6];
    const int* e1_src_r1 = (const int*)d_in[7];
    const int* e1_dst_r1 = (const int*)d_in[8];
    const float* Ws1_r0 = (const float*)d_in[9];
    const float* Wn1_r0 = (const float*)d_in[10];
    const float* Ws1_r1 = (const float*)d_in[11];
    const float* Wn1_r1 = (const float*)d_in[12];
    const float* Ws2_r0 = (const float*)d_in[13];
    const float* Wn2_r0 = (const float*)d_in[14];
    const float* Ws2_r1 = (const float*)d_in[15];
    const float* Wn2_r1 = (const float*)d_in[16];
    const float* b1_r0 = (const float*)d_in[17];
    const float* b1_r1 = (const float*)d_in[18];
    const float* b2_r0 = (const float*)d_in[19];
    const float* b2_r1 = (const float*)d_in[20];
    float* out = (float*)d_out;

    // Workspace (~60.3 MB):
    //   xb      : N0*DD bf16 (25.6 MB); h1 aliases xb (row-for-row, WAR-safe:
    //             each row read only by its owning wave before its store;
    //             clamped-lane reads only corrupt non-stored output columns)
    //   hn      : 2*N1*DD bf16 (25.6 MB), reused across layers
    //   counts  : NSEG_TOT int   \ one contiguous memset
    //   cursor  : NSEG_TOT int   /
    //   row_ptr : NSEG_TOT+4 int
    //   blk_sums: 256 int
    //   eidx    : ETOT int (7.2 MB)
    //   wfrag1/2: 2 x 49152 bf16 (192 KB)
    __hip_bfloat16* xb = (__hip_bfloat16*)d_ws;
    __hip_bfloat16* h1 = xb;
    __hip_bfloat16* hn = xb + (size_t)N0 * DD;
    int* counts   = (int*)(hn + (size_t)2 * N1 * DD);
    int* cursor   = counts + NSEG_TOT;
    int* row_ptr  = cursor + NSEG_TOT;
    int* blk_sums = row_ptr + NSEG_TOT + 4;
    int* eidx     = blk_sums + 256;
    short* wfrag1 = (short*)(eidx + ETOT);
    short* wfrag2 = wfrag1 + 12 * 8 * 64 * 8;

    // 1. zero counts + cursor (contiguous)
    hipMemsetAsync(counts, 0, (size_t)2 * NSEG_TOT * sizeof(int), stream);

    // 2. prologue: cast + hist + weight-prep (independent regions)
    prologue_kernel<<<PROLOGUE_BLOCKS, 256, 0, stream>>>(
        x, xb,
        e0_dst_r0, e0_dst_r1, e1_dst_r0, e1_dst_r1,
        counts,
        Ws1_r0, Ws1_r1, Wn1_r0, Wn1_r1,
        Ws2_r0, Ws2_r1, Wn2_r0, Wn2_r1,
        wfrag1, wfrag2);

    // 3-4. scan
    scan1_kernel<<<SCAN_BLOCKS, 256, 0, stream>>>(counts, row_ptr, blk_sums, NSEG_TOT);
    scan23_kernel<<<SCAN_BLOCKS, 256, 0, stream>>>(row_ptr, blk_sums, NSEG_TOT, SCAN_BLOCKS);

    // 5. fill CSR
    fill_kernel<<<HIST_BLOCKS, 256, 0, stream>>>(
        e0_src_r0, e0_dst_r0, e0_src_r1, e0_dst_r1,
        e1_src_r0, e1_dst_r0, e1_src_r1, e1_dst_r1,
        row_ptr, cursor, eidx);

    // 6-7. layer 1
    aggregate_kernel<<<(2 * N1 + 3) / 4, 256, 0, stream>>>(xb, row_ptr, eidx, hn, 2 * N1);
    mfma_combine_kernel<true, __hip_bfloat16>
        <<<(N1 + 127) / 128, 256, 0, stream>>>(xb, hn, wfrag1, b1_r0, b1_r1, h1, N1);

    // 8-9. layer 2
    aggregate_kernel<<<(2 * N2 + 3) / 4, 256, 0, stream>>>(h1, row_ptr + 2 * N1, eidx, hn, 2 * N2);
    mfma_combine_kernel<false, float>
        <<<(N2 + 127) / 128, 256, 0, stream>>>(h1, hn, wfrag2, b2_r0, b2_r1, out, N2);
}

// Round 7
// 297.070 us; speedup vs baseline: 4.0006x; 1.3663x over previous
//
#include <hip/hip_runtime.h>
#include <hip/hip_bf16.h>

#define N0 100000
#define N1 50000
#define N2 20000
#define DD 128
#define E0 600000
#define E1 300000

#define NSEG_TOT (2 * N1 + 2 * N2)              // 140000 concat CSR segments
#define ETOT     (2 * E0 + 2 * E1)              // 1800000 edges

// counting-sort geometry
#define SEG_SHIFT 9                              // 512 segments per bucket
#define NBK  ((NSEG_TOT + 511) / 512)            // 274 buckets
#define NBK_PAD 288
#define CH   2048                                // edges per chunk
#define NCH  ((ETOT + CH - 1) / CH)              // 879 chunks
#define CAP  13568                               // LDS eidx staging capacity

#define CAST_BLOCKS 12500                        // N0*DD/4 / 256
#define PREP_BLOCKS 48                           // 2*6144/256
#define CNT_BLOCKS  NCH
#define PROLOGUE_BLOCKS (CAST_BLOCKS + PREP_BLOCKS + CNT_BLOCKS)

typedef __attribute__((ext_vector_type(8))) short short8;   // 8 bf16 (4 VGPRs)
typedef __attribute__((ext_vector_type(4))) float floatx4;  // MFMA acc

__device__ __forceinline__ void st2bf(__hip_bfloat16* p, float a, float b) {
    __hip_bfloat162 v;
    v.x = __float2bfloat16(a);
    v.y = __float2bfloat16(b);
    *(__hip_bfloat162*)p = v;
}
__device__ __forceinline__ short bf16bits(float v) {
    __hip_bfloat16 b = __float2bfloat16(v);
    return *(short*)&b;
}
__device__ __forceinline__ float bf2f(unsigned short u) {
    return __uint_as_float(((unsigned int)u) << 16);
}
__device__ __forceinline__ float4 ld4bf(const __hip_bfloat16* p) {  // 8B load
    ushort4 u = *(const ushort4*)p;
    return make_float4(bf2f(u.x), bf2f(u.y), bf2f(u.z), bf2f(u.w));
}
__device__ __forceinline__ void st4bf(__hip_bfloat16* p, float4 v) { // 8B store
    short vs[4];
    vs[0] = bf16bits(v.x); vs[1] = bf16bits(v.y);
    vs[2] = bf16bits(v.z); vs[3] = bf16bits(v.w);
    *(int2*)p = *(int2*)vs;
}

// inclusive Hillis-Steele scan over 256 threads; every thread must call.
__device__ __forceinline__ int scan256(int s, int* sh, int t) {
    sh[t] = s;
    __syncthreads();
    for (int off = 1; off < 256; off <<= 1) {
        int tmp = (t >= off) ? sh[t - off] : 0;
        __syncthreads();
        sh[t] += tmp;
        __syncthreads();
    }
    return sh[t];
}

// ---------------------------------------------------------------------------
// Edge mapping for the concatenated CSR (4 edge lists):
//   [0,E0)          -> L1 rel0, seg base 0
//   [E0,2E0)        -> L1 rel1, seg base N1
//   [2E0,2E0+E1)    -> L2 rel0, seg base 2*N1
//   [2E0+E1,ETOT)   -> L2 rel1, seg base 2*N1+N2
// ---------------------------------------------------------------------------
__device__ __forceinline__ int edge_seg(int e,
    const int* d0, const int* d1, const int* d2, const int* d3)
{
    if (e < E0)               return d0[e];
    if (e < 2 * E0)           return N1 + d1[e - E0];
    if (e < 2 * E0 + E1)      return 2 * N1 + d2[e - 2 * E0];
    return 2 * N1 + N2 + d3[e - 2 * E0 - E1];
}
__device__ __forceinline__ int2 edge_seg_src(int e,
    const int* s0, const int* d0, const int* s1, const int* d1,
    const int* s2, const int* d2, const int* s3, const int* d3)
{
    if (e < E0)               return make_int2(s0[e],            d0[e]);
    if (e < 2 * E0)           return make_int2(s1[e - E0],       N1 + d1[e - E0]);
    if (e < 2 * E0 + E1)      return make_int2(s2[e - 2 * E0],   2 * N1 + d2[e - 2 * E0]);
    int ee = e - 2 * E0 - E1;
    return make_int2(s3[ee], 2 * N1 + N2 + d3[ee]);
}

// ---------------------------------------------------------------------------
// Prologue mega-kernel: [cast | weight-prep | chunk-count], by blockIdx range.
// No global atomics anywhere.
// ---------------------------------------------------------------------------
__global__ __launch_bounds__(256) void prologue_kernel(
    const float* __restrict__ x, __hip_bfloat16* __restrict__ xb,
    const int* __restrict__ d0a, const int* __restrict__ d0b,
    const int* __restrict__ d1a, const int* __restrict__ d1b,
    int* __restrict__ cntmat,
    const float* __restrict__ Ws1a, const float* __restrict__ Ws1b,
    const float* __restrict__ Wn1a, const float* __restrict__ Wn1b,
    const float* __restrict__ Ws2a, const float* __restrict__ Ws2b,
    const float* __restrict__ Wn2a, const float* __restrict__ Wn2b,
    short* __restrict__ wfrag1, short* __restrict__ wfrag2)
{
    __shared__ int hist[NBK_PAD];
    const int bid = blockIdx.x;
    const int t = threadIdx.x;
    if (bid < CAST_BLOCKS) {
        int i = bid * 256 + t;                          // < 3.2M exactly
        float4 v = ((const float4*)x)[i];
        st2bf(xb + (size_t)i * 4, v.x, v.y);
        st2bf(xb + (size_t)i * 4 + 2, v.z, v.w);
    } else if (bid < CAST_BLOCKS + PREP_BLOCKS) {
        int p = (bid - CAST_BLOCKS) * 256 + t;          // < 12288
        int layer = p >= 6144;
        int q = p - layer * 6144;
        int lane = q & 63;
        int mt = (q >> 6) & 7;
        int kc = q >> 9;
        int n = mt * 16 + (lane & 15);
        int k0 = kc * 32 + ((lane >> 4) << 3);
        const float* Wsa = layer ? Ws2a : Ws1a;
        const float* Wsb = layer ? Ws2b : Ws1b;
        const float* Wna = layer ? Wn2a : Wn1a;
        const float* Wnb = layer ? Wn2b : Wn1b;
        short* wf = layer ? wfrag2 : wfrag1;
        short vals[8];
#pragma unroll
        for (int j = 0; j < 8; j++) {
            int k = k0 + j;
            float w;
            if (k < 128)      w = Wsa[k * DD + n] + Wsb[k * DD + n];
            else if (k < 256) w = Wna[(k - 128) * DD + n];
            else              w = Wnb[(k - 256) * DD + n];
            vals[j] = bf16bits(w);
        }
        *(short8*)(wf + (size_t)q * 8) = *(short8*)vals;
    } else {
        const int chunk = bid - CAST_BLOCKS - PREP_BLOCKS;
        for (int l = t; l < NBK_PAD; l += 256) hist[l] = 0;
        __syncthreads();
#pragma unroll
        for (int it = 0; it < CH / 256; it++) {
            int e = chunk * CH + it * 256 + t;
            if (e < ETOT) {
                int seg = edge_seg(e, d0a, d0b, d1a, d1b);
                atomicAdd(&hist[seg >> SEG_SHIFT], 1);   // LDS atomic
            }
        }
        __syncthreads();
        for (int g = t; g < NBK; g += 256)
            cntmat[(size_t)g * NCH + chunk] = hist[g];
    }
}

// ---------------------------------------------------------------------------
// B1: per-bucket exclusive scan across chunks; bucket totals.
// ---------------------------------------------------------------------------
__global__ __launch_bounds__(256) void scan_chunks_kernel(
    const int* __restrict__ cntmat, int* __restrict__ pre, int* __restrict__ tot)
{
    __shared__ int sh[256];
    const int t = threadIdx.x;
    const int g = blockIdx.x;
    const size_t roff = (size_t)g * NCH;
    int v[4]; int s = 0;
#pragma unroll
    for (int i = 0; i < 4; i++) {
        int idx = t * 4 + i;
        v[i] = (idx < NCH) ? cntmat[roff + idx] : 0;
        s += v[i];
    }
    int incl = scan256(s, sh, t);
    int ex = incl - s;
#pragma unroll
    for (int i = 0; i < 4; i++) {
        int idx = t * 4 + i;
        if (idx < NCH) pre[roff + idx] = ex;
        ex += v[i];
    }
    if (t == 255) tot[g] = incl;
}

// builds basel[0..512): exclusive scan of tot (entries >= NBK become ETOT)
__device__ __forceinline__ void build_base(const int* tot, int* basel, int* sh, int t)
{
    int l0 = 2 * t, l1 = 2 * t + 1;
    int v0 = (l0 < NBK) ? tot[l0] : 0;
    int v1 = (l1 < NBK) ? tot[l1] : 0;
    int s = v0 + v1;
    int incl = scan256(s, sh, t);
    int ex = incl - s;
    basel[l0] = ex;
    basel[l1] = ex + v0;
}

// ---------------------------------------------------------------------------
// Pass C: place (src,seg) records bucket-grouped; LDS cursors only.
// ---------------------------------------------------------------------------
__global__ __launch_bounds__(256) void bucket_scatter_kernel(
    const int* __restrict__ s0a, const int* __restrict__ d0a,
    const int* __restrict__ s0b, const int* __restrict__ d0b,
    const int* __restrict__ s1a, const int* __restrict__ d1a,
    const int* __restrict__ s1b, const int* __restrict__ d1b,
    const int* __restrict__ pre, const int* __restrict__ tot,
    int2* __restrict__ ebuf)
{
    __shared__ int sh[256];
    __shared__ int basel[512];
    __shared__ int cur[NBK_PAD];
    const int t = threadIdx.x;
    const int chunk = blockIdx.x;

    build_base(tot, basel, sh, t);
    for (int l = t; l < NBK_PAD; l += 256) cur[l] = 0;
    __syncthreads();

#pragma unroll
    for (int it = 0; it < CH / 256; it++) {
        int e = chunk * CH + it * 256 + t;
        if (e < ETOT) {
            int2 r = edge_seg_src(e, s0a, d0a, s0b, d0b, s1a, d1a, s1b, d1b);
            int g = r.y >> SEG_SHIFT;
            int rk = atomicAdd(&cur[g], 1);              // LDS atomic
            int pos = basel[g] + pre[(size_t)g * NCH + chunk] + rk;
            ebuf[pos] = r;
        }
    }
}

// ---------------------------------------------------------------------------
// Pass D: per-bucket CSR finalize. LDS hist+scan -> row_ptr; LDS-staged
// eidx scatter -> one coalesced global write.
// ---------------------------------------------------------------------------
__global__ __launch_bounds__(256) void csr_finalize_kernel(
    const int2* __restrict__ ebuf, const int* __restrict__ tot,
    int* __restrict__ row_ptr, int* __restrict__ eidx)
{
    __shared__ int sh[256];
    __shared__ int basel[512];
    __shared__ int cnt[512];
    __shared__ int excl[512];
    __shared__ int leidx[CAP];
    const int t = threadIdx.x;
    const int g = blockIdx.x;
    const int l0 = 2 * t, l1 = 2 * t + 1;

    build_base(tot, basel, sh, t);
    cnt[l0] = 0; cnt[l1] = 0;
    __syncthreads();

    const int b0 = basel[g];
    const int b1 = (g + 1 < 512) ? basel[g + 1] : ETOT;  // g+1 <= 274 < 512
    const int Eloc = b1 - b0;
    const int segbase = g << SEG_SHIFT;

    for (int i = t; i < Eloc; i += 256) {
        int2 rec = ebuf[b0 + i];
        atomicAdd(&cnt[rec.y - segbase], 1);             // LDS atomic
    }
    __syncthreads();

    int c0 = cnt[l0], c1 = cnt[l1];
    int ss = c0 + c1;
    int inc2 = scan256(ss, sh, t);
    int ex2 = inc2 - ss;
    excl[l0] = ex2;
    excl[l1] = ex2 + c0;
    __syncthreads();

    int nloc = NSEG_TOT - segbase;
    if (nloc > 512) nloc = 512;
    for (int l = t; l < nloc; l += 256) row_ptr[segbase + l] = b0 + excl[l];
    if (g == 0 && t == 0) row_ptr[NSEG_TOT] = ETOT;

    cnt[l0] = 0; cnt[l1] = 0;                            // reuse as cursor
    __syncthreads();

    if (Eloc <= CAP) {
        for (int i = t; i < Eloc; i += 256) {
            int2 rec = ebuf[b0 + i];
            int l = rec.y - segbase;
            int r = atomicAdd(&cnt[l], 1);
            leidx[excl[l] + r] = rec.x;
        }
        __syncthreads();
        for (int i = t; i < Eloc; i += 256) eidx[b0 + i] = leidx[i];
    } else {                                             // safety fallback
        for (int i = t; i < Eloc; i += 256) {
            int2 rec = ebuf[b0 + i];
            int l = rec.y - segbase;
            int r = atomicAdd(&cnt[l], 1);
            eidx[b0 + excl[l] + r] = rec.x;
        }
    }
}

// ---------------------------------------------------------------------------
// Aggregation: one wave per CSR segment. 8 B/lane loads -> 2 neighbor rows
// per wave-iteration (half-waves), cross-half shfl_xor reduce at the end.
// ---------------------------------------------------------------------------
__global__ __launch_bounds__(256) void aggregate_kernel(
    const __hip_bfloat16* __restrict__ xb,
    const int* __restrict__ row_ptr,
    const int* __restrict__ eidx,
    __hip_bfloat16* __restrict__ hn,
    int nseg)
{
    int wid = (blockIdx.x * 256 + threadIdx.x) >> 6;
    const int lane = threadIdx.x & 63;
    if (wid >= nseg) return;
    wid = __builtin_amdgcn_readfirstlane(wid);

    const int beg = row_ptr[wid];
    const int end = row_ptr[wid + 1];
    const int cnt = end - beg;
    const int half = lane >> 5;
    const int l32 = lane & 31;

    float4 s = make_float4(0.f, 0.f, 0.f, 0.f);
    int k = beg;
    for (; k + 4 <= end; k += 4) {
        int i0 = eidx[k + 0];
        int i1 = eidx[k + 1];
        int i2 = eidx[k + 2];
        int i3 = eidx[k + 3];
        int ra = half ? i1 : i0;
        int rb = half ? i3 : i2;
        float4 va = ld4bf(xb + (long)ra * DD + l32 * 4);
        float4 vb = ld4bf(xb + (long)rb * DD + l32 * 4);
        s.x += va.x + vb.x; s.y += va.y + vb.y;
        s.z += va.z + vb.z; s.w += va.w + vb.w;
    }
    if (k + 2 <= end) {
        int i0 = eidx[k];
        int i1 = eidx[k + 1];
        int r = half ? i1 : i0;
        float4 v = ld4bf(xb + (long)r * DD + l32 * 4);
        s.x += v.x; s.y += v.y; s.z += v.z; s.w += v.w;
        k += 2;
    }
    if (k < end && !half) {
        int i0 = eidx[k];
        float4 v = ld4bf(xb + (long)i0 * DD + l32 * 4);
        s.x += v.x; s.y += v.y; s.z += v.z; s.w += v.w;
    }

    s.x += __shfl_xor(s.x, 32);
    s.y += __shfl_xor(s.y, 32);
    s.z += __shfl_xor(s.z, 32);
    s.w += __shfl_xor(s.w, 32);

    if (!half) {
        const float inv = 1.f / (float)(cnt > 1 ? cnt : 1);
        float4 m = make_float4(s.x * inv, s.y * inv, s.z * inv, s.w * inv);
        st4bf(hn + (long)wid * DD + l32 * 4, m);
    }
}

// ---------------------------------------------------------------------------
// MFMA combine: D[outcol][node] = Wc^T (A-op) x Xcat^T (B-op), K=384.
// ---------------------------------------------------------------------------
template <bool RELU, typename TOUT>
__global__ __launch_bounds__(256) void mfma_combine_kernel(
    const __hip_bfloat16* __restrict__ xself,   // [M][128] bf16
    const __hip_bfloat16* __restrict__ hn,      // [2*M][128] bf16
    const short* __restrict__ wfrag,            // 12*8*64*8 bf16 bits
    const float* __restrict__ b0, const float* __restrict__ b1,
    TOUT* __restrict__ out, int M)
{
    const int t = threadIdx.x;
    const int wave = t >> 6;
    const int lane = t & 63;
    const int nsub = lane & 15;
    const int quad = lane >> 4;
    const int base = blockIdx.x * 128 + wave * 32;

    const int node0 = base + nsub;
    const int node1 = base + 16 + nsub;
    const long n0c = node0 < M ? node0 : M - 1;
    const long n1c = node1 < M ? node1 : M - 1;

    floatx4 acc[2][8];
#pragma unroll
    for (int nt = 0; nt < 2; nt++)
#pragma unroll
        for (int mt = 0; mt < 8; mt++) acc[nt][mt] = (floatx4){0.f, 0.f, 0.f, 0.f};

    for (int kc = 0; kc < 12; kc++) {
        const __hip_bfloat16* src;
        long r0, r1;
        int koff;
        if (kc < 4)      { src = xself; koff = kc * 32;       r0 = n0c;     r1 = n1c; }
        else if (kc < 8) { src = hn;    koff = (kc - 4) * 32; r0 = n0c;     r1 = n1c; }
        else             { src = hn;    koff = (kc - 8) * 32; r0 = M + n0c; r1 = M + n1c; }

        short8 bf0 = *(const short8*)(src + r0 * DD + koff + quad * 8);
        short8 bf1 = *(const short8*)(src + r1 * DD + koff + quad * 8);
        const short* wbase = wfrag + ((size_t)(kc * 8) * 64 + lane) * 8;
#pragma unroll
        for (int mt = 0; mt < 8; mt++) {
            short8 af = *(const short8*)(wbase + (size_t)mt * 64 * 8);
            acc[0][mt] = __builtin_amdgcn_mfma_f32_16x16x32_bf16(af, bf0, acc[0][mt], 0, 0, 0);
            acc[1][mt] = __builtin_amdgcn_mfma_f32_16x16x32_bf16(af, bf1, acc[1][mt], 0, 0, 0);
        }
    }

#pragma unroll
    for (int nt = 0; nt < 2; nt++) {
        int node = (nt == 0) ? node0 : node1;
        if (node >= M) continue;
#pragma unroll
        for (int mt = 0; mt < 8; mt++) {
            int c0 = mt * 16 + quad * 4;
            float4 bb0 = *(const float4*)(b0 + c0);
            float4 bb1 = *(const float4*)(b1 + c0);
            float v0 = acc[nt][mt][0] + bb0.x + bb1.x;
            float v1 = acc[nt][mt][1] + bb0.y + bb1.y;
            float v2 = acc[nt][mt][2] + bb0.z + bb1.z;
            float v3 = acc[nt][mt][3] + bb0.w + bb1.w;
            if (RELU) {
                v0 = v0 > 0.f ? v0 : 0.f;
                v1 = v1 > 0.f ? v1 : 0.f;
                v2 = v2 > 0.f ? v2 : 0.f;
                v3 = v3 > 0.f ? v3 : 0.f;
            }
            TOUT* p = out + (long)node * DD + c0;
            if constexpr (sizeof(TOUT) == 4) {
                *(float4*)p = make_float4(v0, v1, v2, v3);
            } else {
                short vs[4];
                vs[0] = bf16bits(v0); vs[1] = bf16bits(v1);
                vs[2] = bf16bits(v2); vs[3] = bf16bits(v3);
                *(int2*)p = *(int2*)vs;
            }
        }
    }
}

// ---------------------------------------------------------------------------

extern "C" void kernel_launch(void* const* d_in, const int* in_sizes, int n_in,
                              void* d_out, int out_size, void* d_ws, size_t ws_size,
                              hipStream_t stream)
{
    const float* x = (const float*)d_in[0];
    const int* e0_src_r0 = (const int*)d_in[1];
    const int* e0_dst_r0 = (const int*)d_in[2];
    const int* e0_src_r1 = (const int*)d_in[3];
    const int* e0_dst_r1 = (const int*)d_in[4];
    const int* e1_src_r0 = (const int*)d_in[5];
    const int* e1_dst_r0 = (const int*)d_in[6];
    const int* e1_src_r1 = (const int*)d_in[7];
    const int* e1_dst_r1 = (const int*)d_in[8];
    const float* Ws1_r0 = (const float*)d_in[9];
    const float* Wn1_r0 = (const float*)d_in[10];
    const float* Ws1_r1 = (const float*)d_in[11];
    const float* Wn1_r1 = (const float*)d_in[12];
    const float* Ws2_r0 = (const float*)d_in[13];
    const float* Wn2_r0 = (const float*)d_in[14];
    const float* Ws2_r1 = (const float*)d_in[15];
    const float* Wn2_r1 = (const float*)d_in[16];
    const float* b1_r0 = (const float*)d_in[17];
    const float* b1_r1 = (const float*)d_in[18];
    const float* b2_r0 = (const float*)d_in[19];
    const float* b2_r1 = (const float*)d_in[20];
    float* out = (float*)d_out;

    // Workspace (~61 MB):
    //   xb      : N0*DD bf16 (25.6 MB); h1 aliases xb (row-for-row, WAR-safe)
    //   hn      : 2*N1*DD bf16 (25.6 MB); ebuf (ETOT int2, 14.4 MB) aliases hn
    //             (ebuf dead before agg1 writes hn)
    //   eidx    : ETOT int (7.2 MB)
    //   row_ptr : NSEG_TOT+4 int
    //   cntmat  : NBK*NCH int (963 KB)
    //   pre     : NBK*NCH int (963 KB)
    //   tot     : NBK+4 int
    //   wfrag1/2: 2 x 49152 bf16 (192 KB)
    __hip_bfloat16* xb = (__hip_bfloat16*)d_ws;
    __hip_bfloat16* h1 = xb;
    __hip_bfloat16* hn = xb + (size_t)N0 * DD;
    int2* ebuf    = (int2*)hn;
    int* eidx     = (int*)(hn + (size_t)2 * N1 * DD);
    int* row_ptr  = eidx + ETOT;
    int* cntmat   = row_ptr + NSEG_TOT + 4;
    int* pre      = cntmat + NBK * NCH;
    int* tot      = pre + NBK * NCH;
    short* wfrag1 = (short*)(tot + NBK + 4);
    short* wfrag2 = wfrag1 + 12 * 8 * 64 * 8;

    // 1. prologue: cast + weight-prep + chunk counts (no global atomics)
    prologue_kernel<<<PROLOGUE_BLOCKS, 256, 0, stream>>>(
        x, xb,
        e0_dst_r0, e0_dst_r1, e1_dst_r0, e1_dst_r1,
        cntmat,
        Ws1_r0, Ws1_r1, Wn1_r0, Wn1_r1,
        Ws2_r0, Ws2_r1, Wn2_r0, Wn2_r1,
        wfrag1, wfrag2);

    // 2. per-bucket scan across chunks
    scan_chunks_kernel<<<NBK, 256, 0, stream>>>(cntmat, pre, tot);

    // 3. bucket-grouped record scatter
    bucket_scatter_kernel<<<NCH, 256, 0, stream>>>(
        e0_src_r0, e0_dst_r0, e0_src_r1, e0_dst_r1,
        e1_src_r0, e1_dst_r0, e1_src_r1, e1_dst_r1,
        pre, tot, ebuf);

    // 4. per-bucket CSR finalize
    csr_finalize_kernel<<<NBK, 256, 0, stream>>>(ebuf, tot, row_ptr, eidx);

    // 5-6. layer 1
    aggregate_kernel<<<(2 * N1 + 3) / 4, 256, 0, stream>>>(xb, row_ptr, eidx, hn, 2 * N1);
    mfma_combine_kernel<true, __hip_bfloat16>
        <<<(N1 + 127) / 128, 256, 0, stream>>>(xb, hn, wfrag1, b1_r0, b1_r1, h1, N1);

    // 7-8. layer 2
    aggregate_kernel<<<(2 * N2 + 3) / 4, 256, 0, stream>>>(h1, row_ptr + 2 * N1, eidx, hn, 2 * N2);
    mfma_combine_kernel<false, float>
        <<<(N2 + 127) / 128, 256, 0, stream>>>(h1, hn, wfrag2, b2_r0, b2_r1, out, N2);
}